// Round 4
// baseline (262.333 us; speedup 1.0000x reference)
//
#include <hip/hip_runtime.h>

#define N_TOK 4096
#define DIM   1024

typedef __bf16 bf16x8 __attribute__((ext_vector_type(8)));
typedef float  f32x4  __attribute__((ext_vector_type(4)));

__device__ __forceinline__ unsigned short f2bf(float f) {
  union { float f; unsigned u; } v; v.f = f;
  unsigned u = v.u;
  return (unsigned short)((u + 0x7fffu + ((u >> 16) & 1u)) >> 16);
}
__device__ __forceinline__ float bf2f(unsigned short h) {
  union { unsigned u; float f; } v; v.u = ((unsigned)h) << 16;
  return v.f;
}

// async global->LDS, 16 B/lane: lane's data lands at (uniform lds base) + lane*16
__device__ __forceinline__ void gll16(const unsigned short* g,
                                      unsigned short* l) {
  __builtin_amdgcn_global_load_lds(
      (const __attribute__((address_space(1))) unsigned int*)g,
      (__attribute__((address_space(3))) unsigned int*)l, 16, 0, 0);
}

// ---------------------------------------------------------------------------
// prep kernel.  ZERO job now covers out rows 512..4095 (EPI3 z=8 makes
// rows >= 512 atomic-accumulated): 896 blk * 256 thr * 4 float4 =
// 917504 float4 = 3584 rows EXACT.
// ---------------------------------------------------------------------------
#define PB_CVT 0
#define PB_TQ 2048
#define PB_ZERO 5120
#define PB_LSUM 6016
#define PB_BIAS 6020
#define PB_TOTAL 6023

__global__ void prep(const float* __restrict__ x, const float* __restrict__ Wq,
                     const float* __restrict__ Wk, const float* __restrict__ Wv,
                     const float* __restrict__ bq, const float* __restrict__ bk,
                     const float* __restrict__ bv,
                     unsigned short* __restrict__ xb,
                     unsigned short* __restrict__ Wt,
                     float* __restrict__ out, float* __restrict__ ball,
                     float* __restrict__ Lsum) {
  const int b = blockIdx.x;
  const int t = threadIdx.x;
  if (b < PB_TQ) {  // CVT
    const int i = ((b - PB_CVT) * 256 + t) * 8;
    float4 v0 = *(const float4*)(x + i);
    float4 v1 = *(const float4*)(x + i + 4);
    ushort4 r0, r1;
    r0.x = f2bf(v0.x); r0.y = f2bf(v0.y); r0.z = f2bf(v0.z); r0.w = f2bf(v0.w);
    r1.x = f2bf(v1.x); r1.y = f2bf(v1.y); r1.z = f2bf(v1.z); r1.w = f2bf(v1.w);
    *(ushort4*)(xb + i) = r0;
    *(ushort4*)(xb + i + 4) = r1;
  } else if (b < PB_ZERO) {  // transpose one 32x32 tile of one W
    const int which = (b - PB_TQ) >> 10;          // 0,1,2
    const int lb = (b - PB_TQ) & 1023;
    const float* W = (which == 0) ? Wq : (which == 1) ? Wk : Wv;
    unsigned short* D = Wt + (size_t)which * 1024 * 1024;
    __shared__ float tile[32][33];
    const int bx = (lb & 31) * 32, by = (lb >> 5) * 32;
    const int tx = t & 31, ty = t >> 5;  // ty in 0..7
    for (int r = ty; r < 32; r += 8)
      tile[r][tx] = W[(size_t)(by + r) * DIM + bx + tx];
    __syncthreads();
    for (int r = ty; r < 32; r += 8)
      D[(size_t)(bx + r) * DIM + by + tx] = f2bf(tile[tx][r]);
  } else if (b < PB_LSUM) {  // zero out rows >= 512 (3584 rows)
    float4* p = (float4*)(out + (size_t)512 * DIM);
    const int i = ((b - PB_ZERO) * 256 + t) * 4;
#pragma unroll
    for (int c = 0; c < 4; c++) p[i + c] = make_float4(0.f, 0.f, 0.f, 0.f);
  } else if (b < PB_BIAS) {  // Lsum zero
    const int i = ((b - PB_LSUM) * 256 + t) * 4;
    *(float4*)(Lsum + i) = make_float4(0.f, 0.f, 0.f, 0.f);
  } else {  // bias, 4/thread
    const int i = ((b - PB_BIAS) * 256 + t) * 4;
#pragma unroll
    for (int c = 0; c < 4; c++) {
      const int k = i + c;
      if (k < 3072)
        ball[k] = (k < 1024) ? bq[k] * 0.03125f
                             : ((k < 2048) ? bk[k - 1024] : bv[k - 2048]);
    }
  }
}

// ---------------------------------------------------------------------------
// bf16 transpose: Vt[n][m] = V[m][n]  — unchanged.
// ---------------------------------------------------------------------------
__global__ void transpose_bf16(const unsigned short* __restrict__ V, int ldv,
                               unsigned short* __restrict__ Vt, int ldvt) {
  __shared__ unsigned short tile[32][33];
  int bx = blockIdx.x * 32;  // n
  int by = blockIdx.y * 32;  // m
  int tx = threadIdx.x, ty = threadIdx.y;
  for (int r = ty; r < 32; r += 8)
    tile[r][tx] = V[(size_t)(by + r) * ldv + bx + tx];
  __syncthreads();
  for (int r = ty; r < 32; r += 8)
    Vt[(size_t)(bx + r) * ldvt + by + tx] = tile[tx][r];
}

// ---------------------------------------------------------------------------
// 256x256 8-phase GEMM with COUNTED vmcnt (T4 — m218: counted vs drain0 is
// the +38-73% lever; round-3 was the drain0 variant).
//   Staging regrouped by consumer phase (per wave, 8 gll16/K-tile):
//     alpha(t) = B rows w*32..+31 (4) + A rows a0,a0+8 (2)   [P0/P1 data]
//     beta(t)  = A rows a0+64,a0+72 (2)                      [P2/P3 data]
//   where a0 = (w&3)*16 + (w>>2)*128 — A-rows at P0 are {0-63}u{128-191}
//   (wr=1 waves read rows 128+ in P0, NOT the naive lower half).
//   Issue: alpha(t+1) at P0, beta(t+1) at P1.
//   Waits: vmcnt(2) at tile entry (alpha(t) done, beta(t) in flight);
//          vmcnt(8) at P1-end (beta(t) done; alpha+beta(t+1)=8 in flight);
//          never 0 in the main loop (0 only on the last tile's P1-end).
//   T2 swizzle (proven, 0 conflicts): linear gll16 dest, source chunk
//   pre-XOR'd by row&7, read offset kof ^ ((lane&7)<<3).
//   T1 bijective XCD swizzle; T5 setprio around MFMA clusters.
// EPI 0: QKV projection.  EPI 2: U=exp(score) causal + row-sum->Lsum.
// EPI 3: O=(U V)/L, split-K z=8 (chunk 512), atomicAdd when multi.
// ---------------------------------------------------------------------------
#define BK 64

template <int EPI>
__global__ __launch_bounds__(512, 2) void gemm_tn(
    const unsigned short* __restrict__ A, const unsigned short* __restrict__ B,
    void* __restrict__ Cout, const float* __restrict__ bias,
    float* __restrict__ Lsum, int K, int lda, int ldb, int ldc) {
  // ---- bijective XCD swizzle on the (x,y) grid (m204) ----
  const int nwg = gridDim.x * gridDim.y;
  const int orig = blockIdx.y * gridDim.x + blockIdx.x;
  const int q8 = nwg >> 3, r8 = nwg & 7;
  const int xcd = orig & 7;
  const int wg = ((xcd < r8) ? xcd * (q8 + 1) : r8 * (q8 + 1) + (xcd - r8) * q8)
                 + (orig >> 3);
  int bm = wg / gridDim.x;
  int bn = wg % gridDim.x;

  int kbeg, kend;
  bool single = true;
  if (EPI == 3) {
    const int Keff = (bm + 1) * 256;
    kbeg = blockIdx.z * 512;
    if (kbeg >= Keff) return;
    kend = min(kbeg + 512, Keff);
    single = (Keff <= 512);
  } else {
    if (EPI == 2 && bn > bm) return;
    kbeg = 0; kend = K;
  }

  __shared__ __align__(16) unsigned short smA[2][256 * 64];  // 64 KB
  __shared__ __align__(16) unsigned short smB[2][256 * 64];  // 64 KB

  const int t = threadIdx.x;
  const int lane = t & 63, w = t >> 6;   // 8 waves
  const int wr = w >> 2;                  // 0..1 : M half (128 rows)
  const int wc = w & 3;                   // 0..3 : N quarter (64 cols)
  const int lane15 = lane & 15;
  const int kq = (lane >> 4) << 3;        // frag k sub-offset
  const int swz = (lane & 7) << 3;        // read-side XOR (shorts)

  f32x4 acc[8][4] = {};

  // staging: lane covers row lr of an 8-row chunk; column chunk pre-XOR'd
  // so the linear gll16 write matches the swizzled read (read uses row&7
  // == lane&7 on fragment rows; rb = 0 mod 8 keeps r&7 == lr).
  const int lr = lane >> 3;
  const int g8 = ((lane & 7) ^ lr) << 3;
  const unsigned short* gA =
      A + (size_t)((size_t)bm * 256 + lr) * lda + g8 + kbeg;
  const unsigned short* gB =
      B + (size_t)((size_t)bn * 256 + lr) * ldb + g8 + kbeg;

  const int bB = w << 5;                            // B rows w*32..+31
  const int a0 = ((w & 3) << 4) + ((w >> 2) << 7);  // A alpha rows (P0/P1)

  const int nt = (kend - kbeg) / BK;

  auto stgAlpha = [&](int bufi, int tt) {  // 6 gll16: B-all + A(P0/P1 rows)
    const size_t ko = (size_t)tt * BK;
#pragma unroll
    for (int c = 0; c < 4; c++)
      gll16(gB + (size_t)(bB + (c << 3)) * ldb + ko,
            &smB[bufi][(bB + (c << 3)) * 64]);
    gll16(gA + (size_t)a0 * lda + ko, &smA[bufi][a0 * 64]);
    gll16(gA + (size_t)(a0 + 8) * lda + ko, &smA[bufi][(a0 + 8) * 64]);
  };
  auto stgBeta = [&](int bufi, int tt) {   // 2 gll16: A(P2/P3 rows)
    const size_t ko = (size_t)tt * BK;
    gll16(gA + (size_t)(a0 + 64) * lda + ko, &smA[bufi][(a0 + 64) * 64]);
    gll16(gA + (size_t)(a0 + 72) * lda + ko, &smA[bufi][(a0 + 72) * 64]);
  };

  // prologue: tile 0 alpha+beta issued (8 outstanding)
  stgAlpha(0, 0);
  stgBeta(0, 0);

  int buf = 0;
  for (int tt = 0; tt < nt; ++tt) {
    const int nx = tt + 1;
    const unsigned short* sA = smA[buf];
    const unsigned short* sB = smB[buf];
    const int kof0 = kq ^ swz;
    const int kof1 = (32 + kq) ^ swz;
    bf16x8 bA[4], bB0[4], bB1[4];

    // ---- tile entry: alpha(tt) resident (beta(tt)=2 younger in flight)
    asm volatile("s_waitcnt vmcnt(2)" ::: "memory");
    __builtin_amdgcn_s_barrier();
    __builtin_amdgcn_sched_barrier(0);

    // ---- phase 0: acc[0..3] x bB0 (kof0) ----
#pragma unroll
    for (int i = 0; i < 4; i++)
      bA[i] = *(const bf16x8*)&sA[(wr * 128 + i * 16 + lane15) * 64 + kof0];
#pragma unroll
    for (int j = 0; j < 4; j++)
      bB0[j] = *(const bf16x8*)&sB[(wc * 64 + j * 16 + lane15) * 64 + kof0];
    if (nx < nt) stgAlpha(buf ^ 1, nx);
    __builtin_amdgcn_s_barrier();
    asm volatile("s_waitcnt lgkmcnt(0)" ::: "memory");
    __builtin_amdgcn_s_setprio(1);
#pragma unroll
    for (int i = 0; i < 4; i++)
#pragma unroll
      for (int j = 0; j < 4; j++)
        acc[i][j] = __builtin_amdgcn_mfma_f32_16x16x32_bf16(bA[i], bB0[j],
                                                            acc[i][j], 0, 0, 0);
    __builtin_amdgcn_s_setprio(0);
    __builtin_amdgcn_s_barrier();

    // ---- phase 1: acc[0..3] x bB1 (kof1) ----
#pragma unroll
    for (int i = 0; i < 4; i++)
      bA[i] = *(const bf16x8*)&sA[(wr * 128 + i * 16 + lane15) * 64 + kof1];
#pragma unroll
    for (int j = 0; j < 4; j++)
      bB1[j] = *(const bf16x8*)&sB[(wc * 64 + j * 16 + lane15) * 64 + kof1];
    if (nx < nt) stgBeta(buf ^ 1, nx);
    __builtin_amdgcn_s_barrier();
    asm volatile("s_waitcnt lgkmcnt(0)" ::: "memory");
    __builtin_amdgcn_s_setprio(1);
#pragma unroll
    for (int i = 0; i < 4; i++)
#pragma unroll
      for (int j = 0; j < 4; j++)
        acc[i][j] = __builtin_amdgcn_mfma_f32_16x16x32_bf16(bA[i], bB1[j],
                                                            acc[i][j], 0, 0, 0);
    __builtin_amdgcn_s_setprio(0);
    // beta(tt) must be resident for P2; alpha+beta(tt+1)=8 stay in flight.
    if (nx < nt) {
      asm volatile("s_waitcnt vmcnt(8)" ::: "memory");
    } else {
      asm volatile("s_waitcnt vmcnt(0)" ::: "memory");
    }
    __builtin_amdgcn_s_barrier();

    // ---- phase 2: acc[4..7] x bB0 ----
#pragma unroll
    for (int i = 0; i < 4; i++)
      bA[i] = *(const bf16x8*)&sA[(wr * 128 + 64 + i * 16 + lane15) * 64 + kof0];
    __builtin_amdgcn_s_barrier();
    asm volatile("s_waitcnt lgkmcnt(0)" ::: "memory");
    __builtin_amdgcn_s_setprio(1);
#pragma unroll
    for (int i = 0; i < 4; i++)
#pragma unroll
      for (int j = 0; j < 4; j++)
        acc[4 + i][j] = __builtin_amdgcn_mfma_f32_16x16x32_bf16(
            bA[i], bB0[j], acc[4 + i][j], 0, 0, 0);
    __builtin_amdgcn_s_setprio(0);
    __builtin_amdgcn_s_barrier();

    // ---- phase 3: acc[4..7] x bB1 ----
#pragma unroll
    for (int i = 0; i < 4; i++)
      bA[i] = *(const bf16x8*)&sA[(wr * 128 + 64 + i * 16 + lane15) * 64 + kof1];
    __builtin_amdgcn_s_barrier();
    asm volatile("s_waitcnt lgkmcnt(0)" ::: "memory");
    __builtin_amdgcn_s_setprio(1);
#pragma unroll
    for (int i = 0; i < 4; i++)
#pragma unroll
      for (int j = 0; j < 4; j++)
        acc[4 + i][j] = __builtin_amdgcn_mfma_f32_16x16x32_bf16(
            bA[i], bB1[j], acc[4 + i][j], 0, 0, 0);
    __builtin_amdgcn_s_setprio(0);
    // no post barrier: next tile's entry vmcnt(2)+barrier is the sync point
    buf ^= 1;
  }

  // Epilogues. C/D frag layout: col = lane&15, row = (lane>>4)*4 + reg.
  float* Cf = (float*)Cout;
  unsigned short* Ch = (unsigned short*)Cout;
  const int colbase = bn * 256 + wc * 64 + lane15;
  const int rowbase = bm * 256 + wr * 128 + ((lane >> 4) << 2);

  if (EPI == 0) {
#pragma unroll
    for (int i = 0; i < 8; i++)
#pragma unroll
      for (int j = 0; j < 4; j++) {
        const int gc = colbase + j * 16;
        const float cs = (gc < 1024) ? 0.03125f : 1.0f;
        const float bs = bias[gc];
#pragma unroll
        for (int r = 0; r < 4; r++) {
          const int gr = rowbase + i * 16 + r;
          Ch[(size_t)gr * ldc + gc] = f2bf(acc[i][j][r] * cs + bs);
        }
      }
  } else if (EPI == 2) {
    __syncthreads();                 // all LDS reads done; repurpose smA
    float* Lp = (float*)smA;         // 256 floats
    if (t < 256) Lp[t] = 0.f;
    __syncthreads();
#pragma unroll
    for (int i = 0; i < 8; i++)
#pragma unroll
      for (int r = 0; r < 4; r++) {
        const int gr = rowbase + i * 16 + r;
        float sj = 0.f;
#pragma unroll
        for (int j = 0; j < 4; j++) {
          const int gc = colbase + j * 16;
          unsigned short h = 0;
          if (gc <= gr) h = f2bf(__expf(acc[i][j][r]));
          Ch[(size_t)gr * ldc + gc] = h;
          sj += bf2f(h);  // sum rounded value so L matches stored U
        }
        sj += __shfl_xor(sj, 1);
        sj += __shfl_xor(sj, 2);
        sj += __shfl_xor(sj, 4);
        sj += __shfl_xor(sj, 8);
        if (lane15 == 0)
          atomicAdd(&Lp[wr * 128 + i * 16 + ((lane >> 4) << 2) + r], sj);
      }
    __syncthreads();
    if (t < 256) atomicAdd(&Lsum[bm * 256 + t], Lp[t]);
  } else {
#pragma unroll
    for (int i = 0; i < 8; i++)
#pragma unroll
      for (int r = 0; r < 4; r++) {
        const int gr = rowbase + i * 16 + r;
        const float linv = 1.0f / Lsum[gr];
#pragma unroll
        for (int j = 0; j < 4; j++) {
          const int gc = colbase + j * 16;
          const float v = acc[i][j][r] * linv;
          if (single)
            Cf[(size_t)gr * ldc + gc] = v;
          else
            atomicAdd(&Cf[(size_t)gr * ldc + gc], v);
        }
      }
  }
}

// ---------------------------------------------------------------------------
// kernel_launch — 5 launches.  ws layout (ushort elems):
//   [0,4M)    xb [4096x1024]; after concat GEMM, reused as V^T [1024x4096]
//   [4M,7M)   W_all^T = Wq^T | Wk^T | Wv^T  (3072 x 1024)
//   [7M,19M)  Call [4096x3072] = Q | K | V  (Q pre-scaled by 1/32)
//   [19M,35M) Sb [4096x4096]  (U = exp scores)
//   [35M,..)  ball [3072] f32, Lsum [4096] f32
// ---------------------------------------------------------------------------
extern "C" void kernel_launch(void* const* d_in, const int* in_sizes, int n_in,
                              void* d_out, int out_size, void* d_ws,
                              size_t ws_size, hipStream_t stream) {
  (void)in_sizes; (void)n_in; (void)out_size; (void)ws_size;
  const float* x  = (const float*)d_in[0];
  const float* Wq = (const float*)d_in[1];
  const float* bq = (const float*)d_in[2];
  const float* Wk = (const float*)d_in[3];
  const float* bk = (const float*)d_in[4];
  const float* Wv = (const float*)d_in[5];
  const float* bv = (const float*)d_in[6];
  float* out = (float*)d_out;

  const size_t M1 = (size_t)1024 * 1024;
  unsigned short* xb   = (unsigned short*)d_ws;   // 4M elems; later V^T
  unsigned short* Wt   = xb + 4 * M1;             // 3M elems
  unsigned short* Call = Wt + 3 * M1;             // 12M elems
  unsigned short* Sb   = Call + 12 * M1;          // 16M elems
  float* ball          = (float*)(Sb + 16 * M1);  // 3072 f32
  float* Lsum          = ball + 3072;             // 4096 f32

  // 1) all prep in one launch
  prep<<<PB_TOTAL, 256, 0, stream>>>(x, Wq, Wk, Wv, bq, bk, bv, xb, Wt, out,
                                     ball, Lsum);
  // 2) Call = x @ [Wq|Wk|Wv] + ball. 256² tiles.
  gemm_tn<0><<<dim3(12, 16), 512, 0, stream>>>(xb, Wt, Call, ball, nullptr,
                                               DIM, DIM, DIM, 3 * DIM);
  // 3) V^T into the dead xb slot.
  transpose_bf16<<<dim3(32, 128), dim3(32, 8), 0, stream>>>(Call + 2048,
                                                            3 * DIM, xb, N_TOK);
  // 4) U = exp(Q K^T) causal + row sums Lsum. 256² tiles, tri.
  gemm_tn<2><<<dim3(16, 16), 512, 0, stream>>>(Call, Call + 1024, Sb, nullptr,
                                               Lsum, DIM, 3 * DIM, 3 * DIM,
                                               N_TOK);
  // 5) O = (U V) / L, split-K over z (8 chunks of 512 — 288 active blocks).
  gemm_tn<3><<<dim3(4, 16, 8), 512, 0, stream>>>(Sb, xb, out, nullptr, Lsum,
                                                 N_TOK, N_TOK, N_TOK, DIM);
}

// Round 5
// 198.312 us; speedup vs baseline: 1.3228x; 1.3228x over previous
//
#include <hip/hip_runtime.h>

#define N_TOK 4096
#define DIM   1024

typedef __bf16 bf16x8 __attribute__((ext_vector_type(8)));
typedef float  f32x4  __attribute__((ext_vector_type(4)));

__device__ __forceinline__ unsigned short f2bf(float f) {
  union { float f; unsigned u; } v; v.f = f;
  unsigned u = v.u;
  return (unsigned short)((u + 0x7fffu + ((u >> 16) & 1u)) >> 16);
}
__device__ __forceinline__ float bf2f(unsigned short h) {
  union { unsigned u; float f; } v; v.u = ((unsigned)h) << 16;
  return v.f;
}

// async global->LDS, 16 B/lane: lane's data lands at (uniform lds base) + lane*16
__device__ __forceinline__ void gll16(const unsigned short* g,
                                      unsigned short* l) {
  __builtin_amdgcn_global_load_lds(
      (const __attribute__((address_space(1))) unsigned int*)g,
      (__attribute__((address_space(3))) unsigned int*)l, 16, 0, 0);
}

// ---------------------------------------------------------------------------
// prep kernel — round-0 proven version (ZERO covers out rows 1024..4095;
// EPI3 z=4/chunk-1024 direct-stores rows < 1024).
// ---------------------------------------------------------------------------
#define PB_CVT 0
#define PB_TQ 2048
#define PB_ZERO 5120
#define PB_LSUM 5888
#define PB_BIAS 5892
#define PB_TOTAL 5895

__global__ void prep(const float* __restrict__ x, const float* __restrict__ Wq,
                     const float* __restrict__ Wk, const float* __restrict__ Wv,
                     const float* __restrict__ bq, const float* __restrict__ bk,
                     const float* __restrict__ bv,
                     unsigned short* __restrict__ xb,
                     unsigned short* __restrict__ Wt,
                     float* __restrict__ out, float* __restrict__ ball,
                     float* __restrict__ Lsum) {
  const int b = blockIdx.x;
  const int t = threadIdx.x;
  if (b < PB_TQ) {  // CVT
    const int i = ((b - PB_CVT) * 256 + t) * 8;
    float4 v0 = *(const float4*)(x + i);
    float4 v1 = *(const float4*)(x + i + 4);
    ushort4 r0, r1;
    r0.x = f2bf(v0.x); r0.y = f2bf(v0.y); r0.z = f2bf(v0.z); r0.w = f2bf(v0.w);
    r1.x = f2bf(v1.x); r1.y = f2bf(v1.y); r1.z = f2bf(v1.z); r1.w = f2bf(v1.w);
    *(ushort4*)(xb + i) = r0;
    *(ushort4*)(xb + i + 4) = r1;
  } else if (b < PB_ZERO) {  // transpose one 32x32 tile of one W
    const int which = (b - PB_TQ) >> 10;          // 0,1,2
    const int lb = (b - PB_TQ) & 1023;
    const float* W = (which == 0) ? Wq : (which == 1) ? Wk : Wv;
    unsigned short* D = Wt + (size_t)which * 1024 * 1024;
    __shared__ float tile[32][33];
    const int bx = (lb & 31) * 32, by = (lb >> 5) * 32;
    const int tx = t & 31, ty = t >> 5;  // ty in 0..7
    for (int r = ty; r < 32; r += 8)
      tile[r][tx] = W[(size_t)(by + r) * DIM + bx + tx];
    __syncthreads();
    for (int r = ty; r < 32; r += 8)
      D[(size_t)(bx + r) * DIM + by + tx] = f2bf(tile[tx][r]);
  } else if (b < PB_LSUM) {  // zero out rows >= 1024 (3M floats, exact)
    float4* p = (float4*)(out + (size_t)1024 * DIM);
    const int i = ((b - PB_ZERO) * 256 + t) * 4;
#pragma unroll
    for (int c = 0; c < 4; c++) p[i + c] = make_float4(0.f, 0.f, 0.f, 0.f);
  } else if (b < PB_BIAS) {  // Lsum zero
    const int i = ((b - PB_LSUM) * 256 + t) * 4;
    *(float4*)(Lsum + i) = make_float4(0.f, 0.f, 0.f, 0.f);
  } else {  // bias, 4/thread
    const int i = ((b - PB_BIAS) * 256 + t) * 4;
#pragma unroll
    for (int c = 0; c < 4; c++) {
      const int k = i + c;
      if (k < 3072)
        ball[k] = (k < 1024) ? bq[k] * 0.03125f
                             : ((k < 2048) ? bk[k - 1024] : bv[k - 2048]);
    }
  }
}

// ---------------------------------------------------------------------------
// A·B^T MFMA GEMM — round-0 proven structure (128x128 tile, 4 waves, BK=64,
// single-buffer 32 KB LDS, drain loop, VGPR~60, 3-5 resident blocks/CU =
// the cross-block overlap m97/m114 rely on) + proven-safe deltas:
//  * T2 swizzle (verified 0-conflict rounds 1-2): linear gll16 dest,
//    source chunk pre-XOR'd by row&7, read offset ^ ((lane&7)<<3).
//  * EPI0 also emits V^T (ushort4 row-runs) for V-third blocks — replaces
//    the standalone transpose kernel.
//  * EPI2: compact triangular 1D grid (528 real blocks, no dead dispatch).
//  * EPI3: compact 640-item 1D decode of (bn, bm, z), chunk 1024 (z<=4).
// ---------------------------------------------------------------------------
#define BK 64

template <int EPI>
__global__ void gemm_tn(const unsigned short* __restrict__ A,
                        const unsigned short* __restrict__ B,
                        void* __restrict__ Cout,
                        const float* __restrict__ bias,
                        float* __restrict__ Lsum,
                        unsigned short* __restrict__ VT,
                        int K, int lda, int ldb, int ldc) {
  int bm, bn, kbeg, kend;
  bool single = true;
  if (EPI == 3) {
    // compact decode: i -> (bn, q); q -> (bm, z) by chunk-count bands
    const int i = blockIdx.x;       // 0..639
    bn = i & 7;
    const int q = i >> 3;           // 0..79
    int z;
    if (q < 8)       { bm = q;                  z = 0; }
    else if (q < 24) { bm = 8 + ((q - 8) >> 1); z = (q - 8) & 1; }
    else if (q < 48) { bm = 16 + (q - 24) / 3;  z = (q - 24) % 3; }
    else             { bm = 24 + ((q - 48) >> 2); z = (q - 48) & 3; }
    const int Keff = (bm + 1) * 128;
    kbeg = z * 1024;
    kend = min(kbeg + 1024, Keff);
    single = (Keff <= 1024);
  } else if (EPI == 2) {
    // triangular decode: largest bm with bm(bm+1)/2 <= i
    const int i = blockIdx.x;       // 0..527
    float s = sqrtf(8.f * (float)i + 1.f);
    bm = (int)((s - 1.f) * 0.5f);
    while ((bm + 1) * (bm + 2) / 2 <= i) ++bm;
    while (bm * (bm + 1) / 2 > i) --bm;
    bn = i - bm * (bm + 1) / 2;     // 0..bm
    kbeg = 0; kend = K;
  } else {
    bm = blockIdx.y; bn = blockIdx.x;
    kbeg = 0; kend = K;
  }

  __shared__ __align__(16) unsigned short smA[128 * 64];
  __shared__ __align__(16) unsigned short smB[128 * 64];

  const int t = threadIdx.x;
  const int lane = t & 63, w = t >> 6;
  const int wm = (w & 1) * 64, wn = (w >> 1) * 64;

  f32x4 acc[4][4] = {};

  const unsigned short* Ab = A + (size_t)bm * 128 * lda;
  const unsigned short* Bb = B + (size_t)bn * 128 * ldb;

  const int rA = wm + (lane & 15);
  const int rB = wn + (lane & 15);
  const int kquad = (lane >> 4) << 3;
  const int swz = (lane & 7) << 3;   // read-side XOR (shorts)

  // staging source: row lr = lane>>3, chunk pre-XOR'd by lr so the linear
  // gll16 write matches the swizzled read (read rows have row&7 == lane&7).
  const int lr = lane >> 3;
  const int g8 = ((lane & 7) ^ lr) << 3;
  const unsigned short* pa = Ab + (size_t)lr * lda + g8 + kbeg;
  const unsigned short* pb = Bb + (size_t)lr * ldb + g8 + kbeg;

  for (int k0 = kbeg; k0 < kend; k0 += BK) {
    __syncthreads();
#pragma unroll
    for (int m = 0; m < 4; m++) {
      const int r0 = (w << 5) + (m << 3);  // wave-uniform LDS row base
      gll16(pa + (size_t)r0 * lda, smA + r0 * 64);
      gll16(pb + (size_t)r0 * ldb, smB + r0 * 64);
    }
    pa += BK; pb += BK;
    __syncthreads();  // drains vmcnt -> tiles resident

#pragma unroll
    for (int kk = 0; kk < BK; kk += 32) {
      bf16x8 af[4], bfr[4];
      const int kof = (kk + kquad) ^ swz;  // swizzled slot
#pragma unroll
      for (int i = 0; i < 4; i++)
        af[i] = *(const bf16x8*)(&smA[(rA + i * 16) * 64 + kof]);
#pragma unroll
      for (int j = 0; j < 4; j++)
        bfr[j] = *(const bf16x8*)(&smB[(rB + j * 16) * 64 + kof]);
#pragma unroll
      for (int i = 0; i < 4; i++)
#pragma unroll
        for (int j = 0; j < 4; j++)
          acc[i][j] = __builtin_amdgcn_mfma_f32_16x16x32_bf16(af[i], bfr[j],
                                                              acc[i][j], 0, 0, 0);
    }
  }

  // Epilogues. C/D layout: col = lane&15, row = (lane>>4)*4 + reg.
  float* Cf = (float*)Cout;
  unsigned short* Ch = (unsigned short*)Cout;
  const int colbase = bn * 128 + wn + (lane & 15);
  const int rowbase = bm * 128 + wm + ((lane >> 4) << 2);

  if (EPI == 0) {
    const bool isV = (bn >= 16);  // gc >= 2048: V third -> also emit V^T
#pragma unroll
    for (int i = 0; i < 4; i++)
#pragma unroll
      for (int j = 0; j < 4; j++) {
        const int gc = colbase + j * 16;
        const float cs = (gc < 1024) ? 0.03125f : 1.0f;
        const float bs = bias[gc];
        ushort4 h4;
        unsigned short* hp = (unsigned short*)&h4;
#pragma unroll
        for (int r = 0; r < 4; r++) {
          const int gr = rowbase + i * 16 + r;
          const unsigned short h = f2bf(acc[i][j][r] * cs + bs);
          Ch[(size_t)gr * ldc + gc] = h;
          hp[r] = h;
        }
        if (isV) {  // 4 consecutive rows of V^T column-run: one 8B store
          const int gr0 = rowbase + i * 16;
          *(ushort4*)(VT + (size_t)(gc - 2048) * N_TOK + gr0) = h4;
        }
      }
  } else if (EPI == 2) {
    // U = exp(score), causal; block row-sum -> atomicAdd into Lsum.
    __syncthreads();                 // all LDS reads done; repurpose smA
    float* Lp = (float*)smA;         // 128 floats
    if (t < 128) Lp[t] = 0.f;
    __syncthreads();
#pragma unroll
    for (int i = 0; i < 4; i++)
#pragma unroll
      for (int r = 0; r < 4; r++) {
        const int gr = rowbase + i * 16 + r;
        float sj = 0.f;
#pragma unroll
        for (int j = 0; j < 4; j++) {
          const int gc = colbase + j * 16;
          unsigned short h = 0;
          if (gc <= gr) h = f2bf(__expf(acc[i][j][r]));
          Ch[(size_t)gr * ldc + gc] = h;
          sj += bf2f(h);  // sum the rounded value so L matches stored U
        }
        sj += __shfl_xor(sj, 1);
        sj += __shfl_xor(sj, 2);
        sj += __shfl_xor(sj, 4);
        sj += __shfl_xor(sj, 8);
        if ((lane & 15) == 0)
          atomicAdd(&Lp[wm + ((lane >> 4) << 2) + i * 16 + r], sj);
      }
    __syncthreads();
    if (t < 128) atomicAdd(&Lsum[bm * 128 + t], Lp[t]);
  } else {
#pragma unroll
    for (int i = 0; i < 4; i++)
#pragma unroll
      for (int r = 0; r < 4; r++) {
        const int gr = rowbase + i * 16 + r;
        const float linv = 1.0f / Lsum[gr];
#pragma unroll
        for (int j = 0; j < 4; j++) {
          const int gc = colbase + j * 16;
          const float v = acc[i][j][r] * linv;
          if (single)
            Cf[(size_t)gr * ldc + gc] = v;
          else
            atomicAdd(&Cf[(size_t)gr * ldc + gc], v);
        }
      }
  }
}

// ---------------------------------------------------------------------------
// kernel_launch — 4 launches.  ws layout (ushort elems):
//   [0,4M)    xb [4096x1024]; after concat GEMM, reused as V^T [1024x4096]
//             (V^T written by EPI0's epilogue — transpose kernel removed)
//   [4M,7M)   W_all^T = Wq^T | Wk^T | Wv^T  (3072 x 1024)
//   [7M,19M)  Call [4096x3072] = Q | K | V  (Q pre-scaled by 1/32)
//   [19M,35M) Sb [4096x4096]  (U = exp scores)
//   [35M,..)  ball [3072] f32, Lsum [4096] f32
// ---------------------------------------------------------------------------
extern "C" void kernel_launch(void* const* d_in, const int* in_sizes, int n_in,
                              void* d_out, int out_size, void* d_ws,
                              size_t ws_size, hipStream_t stream) {
  (void)in_sizes; (void)n_in; (void)out_size; (void)ws_size;
  const float* x  = (const float*)d_in[0];
  const float* Wq = (const float*)d_in[1];
  const float* bq = (const float*)d_in[2];
  const float* Wk = (const float*)d_in[3];
  const float* bk = (const float*)d_in[4];
  const float* Wv = (const float*)d_in[5];
  const float* bv = (const float*)d_in[6];
  float* out = (float*)d_out;

  const size_t M1 = (size_t)1024 * 1024;
  unsigned short* xb   = (unsigned short*)d_ws;   // 4M elems; later V^T
  unsigned short* Wt   = xb + 4 * M1;             // 3M elems
  unsigned short* Call = Wt + 3 * M1;             // 12M elems
  unsigned short* Sb   = Call + 12 * M1;          // 16M elems
  float* ball          = (float*)(Sb + 16 * M1);  // 3072 f32
  float* Lsum          = ball + 3072;             // 4096 f32

  // 1) all prep in one launch
  prep<<<PB_TOTAL, 256, 0, stream>>>(x, Wq, Wk, Wv, bq, bk, bv, xb, Wt, out,
                                     ball, Lsum);
  // 2) Call = x @ [Wq|Wk|Wv] + ball; V-third also scattered into xb as V^T.
  gemm_tn<0><<<dim3(24, 32), 256, 0, stream>>>(xb, Wt, Call, ball, nullptr,
                                               xb, DIM, DIM, DIM, 3 * DIM);
  // 3) U = exp(Q K^T) causal + row sums Lsum. 528 triangular blocks.
  gemm_tn<2><<<528, 256, 0, stream>>>(Call, Call + 1024, Sb, nullptr, Lsum,
                                      nullptr, DIM, 3 * DIM, 3 * DIM, N_TOK);
  // 4) O = (U V) / L, compact 640-item split-K (chunk 1024).
  gemm_tn<3><<<640, 256, 0, stream>>>(Sb, xb, out, nullptr, Lsum, nullptr,
                                      N_TOK, N_TOK, N_TOK, DIM);
}